// Round 7
// baseline (212.563 us; speedup 1.0000x reference)
//
#include <hip/hip_runtime.h>
#include <math.h>

constexpr int B = 4;
constexpr int N = 8192;
constexpr int KNN = 8;
constexpr int SLICES = 8;              // candidate slices == waves per block
constexpr int CHUNK = 64;              // candidates per chunk
constexpr int NCHUNKS = N / CHUNK;     // 128
constexpr int CPS = NCHUNKS / SLICES;  // 16 chunks per slice
constexpr int BINS = 512;              // 8x8x8 Morton cells

__device__ __forceinline__ int morton9(int x, int y, int z) {
  int c = 0;
#pragma unroll
  for (int b = 0; b < 3; ++b)
    c |= (((x >> b) & 1) << (3 * b + 2)) | (((y >> b) & 1) << (3 * b + 1)) |
         (((z >> b) & 1) << (3 * b + 0));
  return c;
}

// One block per (array, batch): computes packed float4 (x,y,z,|p|^2/2),
// counting-sorts the 8192 points by Morton cell, writes sorted copy and
// per-chunk AABBs. Exactness: any permutation of candidates/queries gives
// the identical top-8 (selection is order-independent, values carried).
__global__ __launch_bounds__(1024) void prep_sort_kernel(
    const float* __restrict__ src, const float* __restrict__ tgt,
    const float* __restrict__ flow, float4* __restrict__ sorted,
    float4* __restrict__ aabb_lo, float4* __restrict__ aabb_hi,
    float* __restrict__ out) {
  int arr = blockIdx.x >> 2;  // 0 = pred(src+flow), 1 = tgt
  int batch = blockIdx.x & 3;
  int t = threadIdx.x;
  if (blockIdx.x == 0 && t == 0) out[0] = 0.0f;

  __shared__ int hist[BINS], scan[BINS], cnt[BINS];

  const float* base = (arr == 0 ? src : tgt) + batch * N * 3;
  const float* fbase = flow + batch * N * 3;

  float4 P[8];
  int code[8];
#pragma unroll
  for (int k = 0; k < 8; ++k) {
    int i = t + k * 1024;
    float x = base[3 * i], y = base[3 * i + 1], z = base[3 * i + 2];
    if (arr == 0) { x += fbase[3 * i]; y += fbase[3 * i + 1]; z += fbase[3 * i + 2]; }
    P[k] = make_float4(x, y, z, 0.5f * (x * x + y * y + z * z));
    int cx = min(max((int)floorf(x + 4.0f), 0), 7);
    int cy = min(max((int)floorf(y + 4.0f), 0), 7);
    int cz = min(max((int)floorf(z + 4.0f), 0), 7);
    code[k] = morton9(cx, cy, cz);
  }
  if (t < BINS) hist[t] = 0;
  __syncthreads();
#pragma unroll
  for (int k = 0; k < 8; ++k) atomicAdd(&hist[code[k]], 1);
  __syncthreads();
  if (t < BINS) scan[t] = hist[t];
  __syncthreads();
  for (int off = 1; off < BINS; off <<= 1) {  // Kogge-Stone inclusive scan
    int v = 0;
    if (t < BINS && t >= off) v = scan[t - off];
    __syncthreads();
    if (t < BINS) scan[t] += v;
    __syncthreads();
  }
  if (t < BINS) cnt[t] = scan[t] - hist[t];  // exclusive prefix
  __syncthreads();

  float4* sout = sorted + (arr * 4 + batch) * N;
#pragma unroll
  for (int k = 0; k < 8; ++k) {
    int dest = atomicAdd(&cnt[code[k]], 1);
    sout[dest] = P[k];
  }
  __threadfence_block();
  __syncthreads();

  // per-chunk AABB: 8 threads per chunk x 8 points each, shfl-reduce
  int ch = t >> 3, sub = t & 7;
  float lx = INFINITY, ly = INFINITY, lz = INFINITY;
  float hx = -INFINITY, hy = -INFINITY, hz = -INFINITY;
#pragma unroll
  for (int k = 0; k < 8; ++k) {
    float4 p = sout[ch * CHUNK + sub * 8 + k];
    lx = fminf(lx, p.x); ly = fminf(ly, p.y); lz = fminf(lz, p.z);
    hx = fmaxf(hx, p.x); hy = fmaxf(hy, p.y); hz = fmaxf(hz, p.z);
  }
#pragma unroll
  for (int m = 1; m < 8; m <<= 1) {
    lx = fminf(lx, __shfl_xor(lx, m)); ly = fminf(ly, __shfl_xor(ly, m));
    lz = fminf(lz, __shfl_xor(lz, m)); hx = fmaxf(hx, __shfl_xor(hx, m));
    hy = fmaxf(hy, __shfl_xor(hy, m)); hz = fmaxf(hz, __shfl_xor(hz, m));
  }
  if (sub == 0) {
    int ai = (arr * 4 + batch) * NCHUNKS + ch;
    aabb_lo[ai] = make_float4(lx, ly, lz, 0.0f);
    aabb_hi[ai] = make_float4(hx, hy, hz, 0.0f);
  }
}

// Insert tv into sorted ascending d[0..7]: d'[0]=min(d0,tv), d'[i]=med3(...).
__device__ __forceinline__ void insert8(float (&d)[KNN], float tv) {
  float n0 = fminf(d[0], tv);
  float n1 = __builtin_amdgcn_fmed3f(d[0], d[1], tv);
  float n2 = __builtin_amdgcn_fmed3f(d[1], d[2], tv);
  float n3 = __builtin_amdgcn_fmed3f(d[2], d[3], tv);
  float n4 = __builtin_amdgcn_fmed3f(d[3], d[4], tv);
  float n5 = __builtin_amdgcn_fmed3f(d[4], d[5], tv);
  float n6 = __builtin_amdgcn_fmed3f(d[5], d[6], tv);
  float n7 = __builtin_amdgcn_fmed3f(d[6], d[7], tv);
  d[0] = n0; d[1] = n1; d[2] = n2; d[3] = n3;
  d[4] = n4; d[5] = n5; d[6] = n6; d[7] = n7;
}

// Block = 8 waves; wave w owns candidate-chunk slice [w*16, w*16+16).
// Per chunk: lane tests dist^2(q, AABB) < 2*d[7]+|q|^2+eps; wave ballot
// skips whole 64-candidate chunk if no lane can improve. Queries are
// Morton-sorted too -> lanes spatially tight -> coherent ballots. Visit
// order starts at the query's own quantile so d[7] tightens immediately.
__global__ __launch_bounds__(512, 4) void chamfer_kernel(
    const float4* __restrict__ sorted, const float4* __restrict__ aabb_lo,
    const float4* __restrict__ aabb_hi, float* __restrict__ out) {
  int blk = blockIdx.x;           // 1024 blocks
  int dir = blk >> 9;             // 0: pred->tgt, 1: tgt->pred
  int batch = (blk >> 7) & 3;
  int qc = blk & 127;             // query chunk
  const float4* __restrict__ qarr = sorted + ((dir == 0 ? 0 : 4) + batch) * N;
  const float4* __restrict__ parr = sorted + ((dir == 0 ? 4 : 0) + batch) * N;
  const float4* __restrict__ alo = aabb_lo + ((dir == 0 ? 4 : 0) + batch) * NCHUNKS;
  const float4* __restrict__ ahi = aabb_hi + ((dir == 0 ? 4 : 0) + batch) * NCHUNKS;

  int lane = threadIdx.x & 63;
  int wave = threadIdx.x >> 6;

  float4 q = qarr[qc * CHUNK + lane];
  float q2 = 2.0f * q.w;

  __shared__ float4 stage[SLICES][CHUNK];      // 8 KB
  __shared__ float part[SLICES][CHUNK][KNN + 1];  // 18 KB

  float d[KNN];
#pragma unroll
  for (int i = 0; i < KNN; ++i) d[i] = INFINITY;

  int j0 = qc >> 3;  // query's quantile mapped into [0,16)
  for (int s = 0; s < CPS; ++s) {
    int j = wave * CPS + ((j0 + s) & (CPS - 1));
    float4 lo = alo[j], hi = ahi[j];
    float ax = fmaxf(fmaxf(lo.x - q.x, q.x - hi.x), 0.0f);
    float ay = fmaxf(fmaxf(lo.y - q.y, q.y - hi.y), 0.0f);
    float az = fmaxf(fmaxf(lo.z - q.z, q.z - hi.z), 0.0f);
    float d2box = __builtin_fmaf(ax, ax, __builtin_fmaf(ay, ay, az * az));
    float r2 = __builtin_fmaf(2.0f, d[KNN - 1], q2) + 1e-4f;  // INF bootstrap
    if (__ballot(d2box < r2)) {
      stage[wave][lane] = parr[j * CHUNK + lane];  // coalesced; wave-sync LDS
#pragma unroll 8
      for (int i = 0; i < CHUNK; ++i) {
        float4 p = stage[wave][i];  // broadcast ds_read_b128
        float tv = __builtin_fmaf(-q.x, p.x,
                   __builtin_fmaf(-q.y, p.y,
                   __builtin_fmaf(-q.z, p.z, p.w)));
        insert8(d, tv);
      }
    }
  }

  // merge 8 slices' sorted top-8 per query through LDS (stride 9)
#pragma unroll
  for (int i = 0; i < KNN; ++i) part[wave][lane][i] = d[i];
  __syncthreads();

  if (wave == 0) {
    float m[KNN];
#pragma unroll
    for (int i = 0; i < KNN; ++i) m[i] = part[0][lane][i];
    for (int s = 1; s < SLICES; ++s) {
#pragma unroll
      for (int i = 0; i < KNN; ++i) insert8(m, part[s][lane][i]);
    }
    float s_ = 0.0f;
#pragma unroll
    for (int i = 0; i < KNN; ++i) {
      float d2 = fmaxf(__builtin_fmaf(2.0f, m[i], q2), 0.0f);
      s_ += sqrtf(d2);
    }
    float val = s_ * (1.0f / KNN);
    for (int off = 32; off; off >>= 1) val += __shfl_down(val, off, 64);
    if (lane == 0) atomicAdd(out, val * (1.0f / (B * N)));
  }
}

extern "C" void kernel_launch(void* const* d_in, const int* in_sizes, int n_in,
                              void* d_out, int out_size, void* d_ws, size_t ws_size,
                              hipStream_t stream) {
  const float* src = (const float*)d_in[0];
  const float* tgt = (const float*)d_in[1];
  const float* flow = (const float*)d_in[2];
  float* out = (float*)d_out;
  float4* sorted = (float4*)d_ws;                    // 2*4*8192 float4 = 1 MB
  float4* aabb_lo = sorted + 2 * 4 * N;              // 1024 float4 = 16 KB
  float4* aabb_hi = aabb_lo + 2 * 4 * NCHUNKS;       // 16 KB

  prep_sort_kernel<<<8, 1024, 0, stream>>>(src, tgt, flow, sorted, aabb_lo,
                                           aabb_hi, out);
  chamfer_kernel<<<2 * B * NCHUNKS, 512, 0, stream>>>(sorted, aabb_lo, aabb_hi,
                                                      out);
}